// Round 7
// baseline (1486.827 us; speedup 1.0000x reference)
//
#include <hip/hip_runtime.h>
#include <math.h>

#define NPTS 4096
#define NB 2
#define K_TOTAL 12
#define BLOCK 256
#define GRID_TILES 2048
#define NSHARD 32
#define WAVES_TOTAL (GRID_TILES * 4)            // 8192
#define WAVES_PER_SHARD (WAVES_TOTAL / NSHARD)  // 256
#define UNITS_CROSS (NB * 64 * 64)              // 8192 cross 64x64 wave-tiles
#define UNITS_TRI 2080                          // 64x64 upper-tri (incl diag) per self matrix
#define UNITS_SELF (4 * UNITS_TRI)              // 8320
#define UNITS_TOTAL (UNITS_CROSS + UNITS_SELF)  // 16512 = 32 * 516 exactly
#define UNITS_PER_SHARD (UNITS_TOTAL / NSHARD)  // 516

// ws layout: floats except counters.
//  [0..24)    sched: 12 x {eps, w}
//  [32..40)   Mbuf: per (pot,batch) stabilization max
//  int[64 + k*16], k<32 : sharded unit counters (64B apart)
//  [640..)    P: 4 pots x NB x NPTS; then V; then S
#define SCHED_OFF 0
#define MBUF_OFF 32
#define CNT_OFF 64
#define P_OFF 640
#define POT_SZ (4 * NB * NPTS)
#define V_OFF (P_OFF + POT_SZ)
#define S_OFF (V_OFF + POT_SZ)

#if __has_builtin(__builtin_amdgcn_exp2f)
#define EXP2F __builtin_amdgcn_exp2f
#else
#define EXP2F exp2f
#endif
#if __has_builtin(__builtin_amdgcn_logf)
#define LOG2F __builtin_amdgcn_logf
#else
#define LOG2F log2f
#endif
#if __has_builtin(__builtin_amdgcn_sqrtf)
#define FSQRTF __builtin_amdgcn_sqrtf
#else
#define FSQRTF sqrtf
#endif

#define BASE_LOGW -8.31776616671934f  // -log(4096), N==M
#define LOG2E 1.4426950408889634f
#define LN2 0.69314718055994531f

// ---------------------------------------------------------------------------
// Kernel A: zero P/S, V=1, Mbuf=base, seed shard counters. Diameter (f32,
// matching numpy) + eps schedule (f64, matching np.arange/np.exp).
// ---------------------------------------------------------------------------
__global__ __launch_bounds__(BLOCK) void k_init(
    const float2* __restrict__ x, const float2* __restrict__ y, float* ws)
{
  const int tid = threadIdx.x;
  for (int i = tid; i < POT_SZ; i += BLOCK) {
    ws[P_OFF + i] = 0.0f;
    ws[S_OFF + i] = 0.0f;
    ws[V_OFF + i] = 1.0f;
  }
  if (tid < 8) ws[MBUF_OFF + tid] = BASE_LOGW;
  if (tid < NSHARD)
    ((int*)ws)[CNT_OFF + tid * 16] = tid * UNITS_PER_SHARD + WAVES_PER_SHARD;

  float mnx = 1e30f, mny = 1e30f, mxx = -1e30f, mxy = -1e30f;
  for (int i = tid; i < NB * NPTS; i += BLOCK) {
    float2 p = x[i];
    mnx = fminf(mnx, p.x); mxx = fmaxf(mxx, p.x);
    mny = fminf(mny, p.y); mxy = fmaxf(mxy, p.y);
    float2 q = y[i];
    mnx = fminf(mnx, q.x); mxx = fmaxf(mxx, q.x);
    mny = fminf(mny, q.y); mxy = fmaxf(mxy, q.y);
  }
  for (int o = 32; o; o >>= 1) {
    mnx = fminf(mnx, __shfl_xor(mnx, o, 64));
    mxx = fmaxf(mxx, __shfl_xor(mxx, o, 64));
    mny = fminf(mny, __shfl_xor(mny, o, 64));
    mxy = fmaxf(mxy, __shfl_xor(mxy, o, 64));
  }
  __shared__ float r[4][4];
  const int wave = tid >> 6, lane = tid & 63;
  if (lane == 0) { r[0][wave] = mnx; r[1][wave] = mxx; r[2][wave] = mny; r[3][wave] = mxy; }
  __syncthreads();
  if (tid == 0) {
    mnx = fminf(fminf(r[0][0], r[0][1]), fminf(r[0][2], r[0][3]));
    mxx = fmaxf(fmaxf(r[1][0], r[1][1]), fmaxf(r[1][2], r[1][3]));
    mny = fminf(fminf(r[2][0], r[2][1]), fminf(r[2][2], r[2][3]));
    mxy = fmaxf(fmaxf(r[3][0], r[3][1]), fmaxf(r[3][2], r[3][3]));
    float rx = mxx - mnx, ry = mxy - mny;
    float dia = sqrtf(rx * rx + ry * ry);

    double a = log((double)dia);
    double stop = log(0.05);
    double stp = log(0.5);
    int cnt = (int)ceil((stop - a) / stp);  // data: cnt == 8
    if (cnt < 0) cnt = 0;
    if (cnt > K_TOTAL - 4) cnt = K_TOTAL - 4;

    float* sch = ws + SCHED_OFF;
    sch[0] = dia; sch[1] = 0.0f;   // init: direct assign at eps=diameter
    sch[2] = dia; sch[3] = 0.5f;   // annealing loop, w=0.5
    for (int k = 0; k < cnt; k++) {
      sch[2 * (2 + k)] = (float)exp(a + (double)k * stp);
      sch[2 * (2 + k) + 1] = 0.5f;
    }
    sch[2 * (2 + cnt)] = 0.05f; sch[2 * (2 + cnt) + 1] = 0.5f;
    for (int s = 3 + cnt; s < K_TOTAL - 1; s++) { sch[2 * s] = 0.05f; sch[2 * s + 1] = 1.0f; }
    sch[2 * (K_TOTAL - 1)] = 0.05f; sch[2 * (K_TOTAL - 1) + 1] = 0.0f;  // final extrapolation
  }
}

// ---------------------------------------------------------------------------
// Kernel B: waveized. Each WAVE independently processes 64x64 tiles: fragments
// loaded straight from global (L1/L2-hot), K computed once per pair, row sums
// reduced via shfl_xor over col-groups, col sums over row-groups; results
// accumulated to S via device atomics. NO LDS, NO barriers -> waves drift
// freely; sharded counters (32 x 516 units) give near-perfect packing.
// ---------------------------------------------------------------------------
__global__ __launch_bounds__(BLOCK, 4) void k_tiles(
    const float2* __restrict__ xpts, const float2* __restrict__ ypts,
    float* __restrict__ ws, int stepi)
{
  const int lane = threadIdx.x & 63;
  const int gwave = blockIdx.x * 4 + (threadIdx.x >> 6);
  const int shard = gwave & (NSHARD - 1);
  const int rank = gwave >> 5;               // 0..255, < UNITS_PER_SHARD
  int* cnt = (int*)ws + CNT_OFF + shard * 16;
  const int lim = (shard + 1) * UNITS_PER_SHARD;

  const float eps = ws[SCHED_OFF + 2 * stepi];
  const float scale = LOG2E / eps;
  float* V = ws + V_OFF;
  float* S = ws + S_OFF;
  const int rg = lane >> 3, cg = lane & 7;

  int u = shard * UNITS_PER_SHARD + rank;    // seeded first unit (no atomic storm)
  while (u < lim) {
    // prefetch next unit id; latency hides under this unit's compute
    int un = 0;
    if (lane == 0) un = atomicAdd(cnt, 1);
    un = __shfl(un, 0, 64);

    // ---- decode unit ----
    const float2 *rowp, *colp;
    const float *vrow, *vcol;
    float *srow, *scol;
    int ti, tj; bool dual;
    if (u < UNITS_CROSS) {
      const int b = u >> 12, r = u & 4095;
      ti = r >> 6; tj = r & 63;
      rowp = xpts + b * NPTS; colp = ypts + b * NPTS;
      vrow = V + b * NPTS;        vcol = V + (NB + b) * NPTS;
      srow = S + b * NPTS;        scol = S + (NB + b) * NPTS;
      dual = true;
    } else {
      const int u2 = u - UNITS_CROSS;
      const int m = u2 / UNITS_TRI;
      const int r = u2 - m * UNITS_TRI;
      int a = (int)(64.5 - sqrt(64.5 * 64.5 - 2.0 * (double)r));
      if (a < 0) a = 0;
      while ((a + 1) * (129 - (a + 1)) / 2 <= r) a++;
      while (a * (129 - a) / 2 > r) a--;
      ti = a; tj = a + (r - a * (129 - a) / 2);
      const int mat = m >> 1, b = m & 1;
      const float2* pts = mat ? ypts : xpts;
      rowp = pts + b * NPTS; colp = rowp;
      const int po = (2 + mat) * NB + b;
      vrow = V + po * NPTS; vcol = vrow;
      srow = S + po * NPTS; scol = srow;
      dual = (ti != tj);
    }
    const int rbase = ti * 64 + rg * 8;
    const int cbase = tj * 64 + cg * 8;

    // ---- fragment loads: 16B vector loads, L1-broadcast within groups ----
    float rx[8], ry[8], rv[8], cx[8], cy[8], cv[8];
    {
      const float4* rp = (const float4*)(rowp + rbase);
      const float4* cp = (const float4*)(colp + cbase);
#pragma unroll
      for (int q = 0; q < 4; q++) {
        float4 A = rp[q];
        rx[2*q]   = A.x * scale; ry[2*q]   = A.y * scale;
        rx[2*q+1] = A.z * scale; ry[2*q+1] = A.w * scale;
        float4 Bv = cp[q];
        cx[2*q]   = Bv.x * scale; cy[2*q]   = Bv.y * scale;
        cx[2*q+1] = Bv.z * scale; cy[2*q+1] = Bv.w * scale;
      }
      const float4* vr = (const float4*)(vrow + rbase);
      const float4* vc = (const float4*)(vcol + cbase);
      float4 v0 = vr[0], v1 = vr[1], w0 = vc[0], w1 = vc[1];
      rv[0]=v0.x; rv[1]=v0.y; rv[2]=v0.z; rv[3]=v0.w;
      rv[4]=v1.x; rv[5]=v1.y; rv[6]=v1.z; rv[7]=v1.w;
      cv[0]=w0.x; cv[1]=w0.y; cv[2]=w0.z; cv[3]=w0.w;
      cv[4]=w1.x; cv[5]=w1.y; cv[6]=w1.z; cv[7]=w1.w;
    }

    float racc[8], cacc[8];
#pragma unroll
    for (int q = 0; q < 8; q++) { racc[q] = 0.0f; cacc[q] = 0.0f; }

#pragma unroll
    for (int q = 0; q < 8; q++) {
#pragma unroll
      for (int p = 0; p < 8; p++) {
        float dx = rx[q] - cx[p];
        float dy = ry[q] - cy[p];
        float K = EXP2F(-FSQRTF(fmaf(dx, dx, dy * dy)));
        racc[q] = fmaf(K, cv[p], racc[q]);
        cacc[p] = fmaf(K, rv[q], cacc[p]);
      }
    }

    // ---- row sums: reduce over col-groups (lane bits 0..2) ----
#pragma unroll
    for (int m = 1; m <= 4; m <<= 1)
#pragma unroll
      for (int q = 0; q < 8; q++) racc[q] += __shfl_xor(racc[q], m, 64);
    if (cg == 0) {
#pragma unroll
      for (int q = 0; q < 8; q++) atomicAdd(&srow[rbase + q], racc[q]);
    }
    // ---- col sums: reduce over row-groups (lane bits 3..5) ----
    if (dual) {
#pragma unroll
      for (int m = 8; m <= 32; m <<= 1)
#pragma unroll
        for (int q = 0; q < 8; q++) cacc[q] += __shfl_xor(cacc[q], m, 64);
      if (rg == 0) {
#pragma unroll
        for (int q = 0; q < 8; q++) atomicAdd(&scol[cbase + q], cacc[q]);
      }
    }
    u = un;
  }
}

// ---------------------------------------------------------------------------
// Kernel C: per (pot,batch): finalize f from S, mix with w, write P in place;
// build next step's V = exp2((logw + P/eps_next - Mnew)*log2e); zero S;
// block 0 re-arms the shard counters.
// ---------------------------------------------------------------------------
__global__ __launch_bounds__(BLOCK) void k_combine(float* __restrict__ ws, int stepi)
{
  const int pb = blockIdx.x;
  const int p = pb >> 1, b = pb & 1;
  const int tid = threadIdx.x;
  if (pb == 0 && tid < NSHARD)
    ((int*)ws)[CNT_OFF + tid * 16] = tid * UNITS_PER_SHARD + WAVES_PER_SHARD;

  const float eps = ws[SCHED_OFF + 2 * stepi];
  const float w = ws[SCHED_OFF + 2 * stepi + 1];
  int ni = stepi + 1; if (ni > K_TOTAL - 1) ni = K_TOTAL - 1;
  const float inv_eps_n = 1.0f / ws[SCHED_OFF + 2 * ni];
  const float Mh = ws[MBUF_OFF + pb];

  float* Pp = ws + P_OFF + (p * NB + b) * NPTS;
  float* Vp = ws + V_OFF + (p * NB + b) * NPTS;
  float* Sp = ws + S_OFF + (p * NB + b) * NPTS;

  float h[16];
  float lmax = -1e30f;
#pragma unroll
  for (int q = 0; q < 16; q++) {
    const int r = q * BLOCK + tid;
    float s = fmaxf(Sp[r], 1e-37f);
    float ft = -eps * fmaf(LN2, LOG2F(s), Mh);
    float fo = Pp[r];
    float fn = (w >= 1.0f) ? fo : fmaf(w, fo, (1.0f - w) * ft);
    Pp[r] = fn;
    Sp[r] = 0.0f;
    h[q] = fmaf(fn, inv_eps_n, BASE_LOGW);
    lmax = fmaxf(lmax, h[q]);
  }
  for (int o = 32; o; o >>= 1) lmax = fmaxf(lmax, __shfl_xor(lmax, o, 64));
  __shared__ float red[4];
  if ((tid & 63) == 0) red[tid >> 6] = lmax;
  __syncthreads();
  const float M = fmaxf(fmaxf(red[0], red[1]), fmaxf(red[2], red[3]));
#pragma unroll
  for (int q = 0; q < 16; q++) {
    const int r = q * BLOCK + tid;
    Vp[r] = EXP2F((h[q] - M) * LOG2E);
  }
  if (tid == 0) ws[MBUF_OFF + pb] = M;
}

// ---------------------------------------------------------------------------
// Kernel D: out = mean_b [ (1/N) sum(f_ba - f_aa) + (1/M) sum(g_ab - g_bb) ]
// ---------------------------------------------------------------------------
__global__ __launch_bounds__(BLOCK) void k_reduce(
    const float* __restrict__ pot, float* __restrict__ out)
{
  const int tid = threadIdx.x;
  double acc = 0.0;
  for (int i = tid; i < POT_SZ; i += BLOCK) {
    double v = (double)pot[i];
    acc += (i < 2 * NB * NPTS) ? v : -v;  // +f_ba +g_ab -f_aa -g_bb
  }
  for (int o = 32; o; o >>= 1) acc += __shfl_xor(acc, o, 64);
  __shared__ double rd[4];
  const int wave = tid >> 6, lane = tid & 63;
  if (lane == 0) rd[wave] = acc;
  __syncthreads();
  if (tid == 0) out[0] = (float)((rd[0] + rd[1] + rd[2] + rd[3]) / (double)(NB * NPTS));
}

extern "C" void kernel_launch(void* const* d_in, const int* in_sizes, int n_in,
                              void* d_out, int out_size, void* d_ws, size_t ws_size,
                              hipStream_t stream)
{
  const float2* x = (const float2*)d_in[0];  // pre (2,4096,2)
  const float2* y = (const float2*)d_in[1];  // gt  (2,4096,2)
  float* ws = (float*)d_ws;

  k_init<<<1, BLOCK, 0, stream>>>(x, y, ws);

  for (int s = 0; s < K_TOTAL; s++) {
    k_tiles<<<GRID_TILES, BLOCK, 0, stream>>>(x, y, ws, s);
    k_combine<<<8, BLOCK, 0, stream>>>(ws, s);
  }
  k_reduce<<<1, BLOCK, 0, stream>>>(ws + P_OFF, (float*)d_out);
}

// Round 8
// 616.748 us; speedup vs baseline: 2.4108x; 2.4108x over previous
//
#include <hip/hip_runtime.h>
#include <math.h>

#define NPTS 4096
#define NB 2
#define K_TOTAL 12
#define BLOCK 256
#define GRID_TILES 2048
#define WAVES_TOTAL (GRID_TILES * 4)            // 8192
#define UNITS_CROSS (NB * 64 * 64)              // 8192 cross 64x64 wave-tiles
#define UNITS_TRI 2080                          // 64x64 upper-tri (incl diag) per self matrix
#define UNITS_TOTAL (UNITS_CROSS + 4 * UNITS_TRI)  // 16512 = 2*8192 + 128

// ws layout (floats):
//  [0..24)    sched: 12 x {eps, w}
//  [32..40)   Mbuf: per (pot,batch) stabilization max
//  [64..)     P: 4 pots x NB x NPTS
//  [..)       V: exp2((h-M)*log2e) per source pot
//  [65792..)  PART: 8 (pb) x 64 stripes x 64 contribs x 64 rows
#define SCHED_OFF 0
#define MBUF_OFF 32
#define P_OFF 64
#define POT_SZ (4 * NB * NPTS)
#define V_OFF (P_OFF + POT_SZ)
#define PART_OFF 65792
#define PART_PB (64 * 64 * 64)   // 262144 floats per (pot,batch)

#if __has_builtin(__builtin_amdgcn_exp2f)
#define EXP2F __builtin_amdgcn_exp2f
#else
#define EXP2F exp2f
#endif
#if __has_builtin(__builtin_amdgcn_logf)
#define LOG2F __builtin_amdgcn_logf
#else
#define LOG2F log2f
#endif
#if __has_builtin(__builtin_amdgcn_sqrtf)
#define FSQRTF __builtin_amdgcn_sqrtf
#else
#define FSQRTF sqrtf
#endif

#define BASE_LOGW -8.31776616671934f  // -log(4096), N==M
#define LOG2E 1.4426950408889634f
#define LN2 0.69314718055994531f

// ---------------------------------------------------------------------------
// Kernel A: zero P, V=1, Mbuf=base. Diameter (f32, matching numpy) + eps
// schedule (f64, matching np.arange/np.exp). PART needs no init: every slot
// is written by k_tiles before k_combine reads it.
// ---------------------------------------------------------------------------
__global__ __launch_bounds__(BLOCK) void k_init(
    const float2* __restrict__ x, const float2* __restrict__ y, float* ws)
{
  const int tid = threadIdx.x;
  for (int i = tid; i < POT_SZ; i += BLOCK) {
    ws[P_OFF + i] = 0.0f;
    ws[V_OFF + i] = 1.0f;
  }
  if (tid < 8) ws[MBUF_OFF + tid] = BASE_LOGW;

  float mnx = 1e30f, mny = 1e30f, mxx = -1e30f, mxy = -1e30f;
  for (int i = tid; i < NB * NPTS; i += BLOCK) {
    float2 p = x[i];
    mnx = fminf(mnx, p.x); mxx = fmaxf(mxx, p.x);
    mny = fminf(mny, p.y); mxy = fmaxf(mxy, p.y);
    float2 q = y[i];
    mnx = fminf(mnx, q.x); mxx = fmaxf(mxx, q.x);
    mny = fminf(mny, q.y); mxy = fmaxf(mxy, q.y);
  }
  for (int o = 32; o; o >>= 1) {
    mnx = fminf(mnx, __shfl_xor(mnx, o, 64));
    mxx = fmaxf(mxx, __shfl_xor(mxx, o, 64));
    mny = fminf(mny, __shfl_xor(mny, o, 64));
    mxy = fmaxf(mxy, __shfl_xor(mxy, o, 64));
  }
  __shared__ float r[4][4];
  const int wave = tid >> 6, lane = tid & 63;
  if (lane == 0) { r[0][wave] = mnx; r[1][wave] = mxx; r[2][wave] = mny; r[3][wave] = mxy; }
  __syncthreads();
  if (tid == 0) {
    mnx = fminf(fminf(r[0][0], r[0][1]), fminf(r[0][2], r[0][3]));
    mxx = fmaxf(fmaxf(r[1][0], r[1][1]), fmaxf(r[1][2], r[1][3]));
    mny = fminf(fminf(r[2][0], r[2][1]), fminf(r[2][2], r[2][3]));
    mxy = fmaxf(fmaxf(r[3][0], r[3][1]), fmaxf(r[3][2], r[3][3]));
    float rx = mxx - mnx, ry = mxy - mny;
    float dia = sqrtf(rx * rx + ry * ry);

    double a = log((double)dia);
    double stop = log(0.05);
    double stp = log(0.5);
    int cnt = (int)ceil((stop - a) / stp);  // data: cnt == 8
    if (cnt < 0) cnt = 0;
    if (cnt > K_TOTAL - 4) cnt = K_TOTAL - 4;

    float* sch = ws + SCHED_OFF;
    sch[0] = dia; sch[1] = 0.0f;   // init: direct assign at eps=diameter
    sch[2] = dia; sch[3] = 0.5f;   // annealing loop, w=0.5
    for (int k = 0; k < cnt; k++) {
      sch[2 * (2 + k)] = (float)exp(a + (double)k * stp);
      sch[2 * (2 + k) + 1] = 0.5f;
    }
    sch[2 * (2 + cnt)] = 0.05f; sch[2 * (2 + cnt) + 1] = 0.5f;
    for (int s = 3 + cnt; s < K_TOTAL - 1; s++) { sch[2 * s] = 0.05f; sch[2 * s + 1] = 1.0f; }
    sch[2 * (K_TOTAL - 1)] = 0.05f; sch[2 * (K_TOTAL - 1) + 1] = 0.0f;  // final extrapolation
  }
}

// ---------------------------------------------------------------------------
// Kernel B: static waveized tiles. Wave gw owns units {gw, gw+8192} plus one
// of the 128 leftovers if gw%64==0. Unit = 64x64 tile: fragments straight
// from global (L1/L2-hot), K = exp2(-sqrt(d2s)) once per pair, row sums
// shfl-reduced over col-groups, col sums over row-groups, then ONE coalesced
// 256B plain store each into PART (every slot written exactly once per step).
// No LDS, no barriers, no atomics, no counters.
// ---------------------------------------------------------------------------
__global__ __launch_bounds__(BLOCK, 4) void k_tiles(
    const float2* __restrict__ xpts, const float2* __restrict__ ypts,
    float* __restrict__ ws, int stepi)
{
  const int lane = threadIdx.x & 63;
  const int gw = blockIdx.x * 4 + (threadIdx.x >> 6);
  const float eps = ws[SCHED_OFF + 2 * stepi];
  const float scale = LOG2E / eps;
  const float* V = ws + V_OFF;
  float* PART = ws + PART_OFF;
  const int rg = lane >> 3, cg = lane & 7;

  int units[3];
  units[0] = gw;
  units[1] = gw + WAVES_TOTAL;
  units[2] = ((gw & 63) == 0) ? (2 * WAVES_TOTAL + (gw >> 6)) : -1;

  for (int it = 0; it < 3; it++) {
    const int u = units[it];
    if (u < 0 || u >= UNITS_TOTAL) continue;

    // ---- decode unit ----
    const float2 *rowp, *colp;
    const float *vrow, *vcol;
    int ti, tj, pbR, pbC; bool dual;
    if (u < UNITS_CROSS) {
      const int b = u >> 12, r = u & 4095;
      ti = r >> 6; tj = r & 63;
      rowp = xpts + b * NPTS; colp = ypts + b * NPTS;
      vrow = V + b * NPTS;            vcol = V + (NB + b) * NPTS;
      pbR = b; pbC = NB + b;          // f_ba rows, g_ab cols
      dual = true;
    } else {
      const int u2 = u - UNITS_CROSS;
      const int m = u2 / UNITS_TRI;
      const int r = u2 - m * UNITS_TRI;
      int a = (int)(64.5 - sqrt(64.5 * 64.5 - 2.0 * (double)r));
      if (a < 0) a = 0;
      while ((a + 1) * (129 - (a + 1)) / 2 <= r) a++;
      while (a * (129 - a) / 2 > r) a--;
      ti = a; tj = a + (r - a * (129 - a) / 2);
      const int mat = m >> 1, b = m & 1;
      const float2* pts = mat ? ypts : xpts;
      rowp = pts + b * NPTS; colp = rowp;
      const int po = (2 + mat) * NB + b;
      vrow = V + po * NPTS; vcol = vrow;
      pbR = po; pbC = po;
      dual = (ti != tj);
    }
    const int rbase = ti * 64 + rg * 8;
    const int cbase = tj * 64 + cg * 8;

    // ---- fragment loads: 16B vector loads, L1-broadcast within groups ----
    float rx[8], ry[8], rv[8], cx[8], cy[8], cv[8];
    {
      const float4* rp = (const float4*)(rowp + rbase);
      const float4* cp = (const float4*)(colp + cbase);
#pragma unroll
      for (int q = 0; q < 4; q++) {
        float4 A = rp[q];
        rx[2*q]   = A.x * scale; ry[2*q]   = A.y * scale;
        rx[2*q+1] = A.z * scale; ry[2*q+1] = A.w * scale;
        float4 Bv = cp[q];
        cx[2*q]   = Bv.x * scale; cy[2*q]   = Bv.y * scale;
        cx[2*q+1] = Bv.z * scale; cy[2*q+1] = Bv.w * scale;
      }
      const float4* vr = (const float4*)(vrow + rbase);
      const float4* vc = (const float4*)(vcol + cbase);
      float4 v0 = vr[0], v1 = vr[1], w0 = vc[0], w1 = vc[1];
      rv[0]=v0.x; rv[1]=v0.y; rv[2]=v0.z; rv[3]=v0.w;
      rv[4]=v1.x; rv[5]=v1.y; rv[6]=v1.z; rv[7]=v1.w;
      cv[0]=w0.x; cv[1]=w0.y; cv[2]=w0.z; cv[3]=w0.w;
      cv[4]=w1.x; cv[5]=w1.y; cv[6]=w1.z; cv[7]=w1.w;
    }

    float racc[8], cacc[8];
#pragma unroll
    for (int q = 0; q < 8; q++) { racc[q] = 0.0f; cacc[q] = 0.0f; }

#pragma unroll
    for (int q = 0; q < 8; q++) {
#pragma unroll
      for (int p = 0; p < 8; p++) {
        float dx = rx[q] - cx[p];
        float dy = ry[q] - cy[p];
        float K = EXP2F(-FSQRTF(fmaf(dx, dx, dy * dy)));
        racc[q] = fmaf(K, cv[p], racc[q]);
        cacc[p] = fmaf(K, rv[q], cacc[p]);
      }
    }

    // ---- row sums: reduce over col-groups (lane bits 0..2), then each lane
    // selects its own row (register l&7 of its own octet) -> coalesced store
#pragma unroll
    for (int m = 1; m <= 4; m <<= 1)
#pragma unroll
      for (int q = 0; q < 8; q++) racc[q] += __shfl_xor(racc[q], m, 64);
    {
      float sel = racc[0];
#pragma unroll
      for (int q = 1; q < 8; q++) sel = (cg == q) ? racc[q] : sel;
      PART[pbR * PART_PB + ti * 4096 + tj * 64 + lane] = sel;
    }

    // ---- col sums: reduce over row-groups (bits 3..5); lane l needs reg
    // (l&7) from lane (l>>3) -> 8 shfls + select -> coalesced store
    if (dual) {
#pragma unroll
      for (int m = 8; m <= 32; m <<= 1)
#pragma unroll
        for (int q = 0; q < 8; q++) cacc[q] += __shfl_xor(cacc[q], m, 64);
      float sel = __shfl(cacc[0], rg, 64);
#pragma unroll
      for (int q = 1; q < 8; q++) {
        float t = __shfl(cacc[q], rg, 64);
        sel = (cg == q) ? t : sel;
      }
      PART[pbC * PART_PB + tj * 4096 + ti * 64 + lane] = sel;
    }
  }
}

// ---------------------------------------------------------------------------
// Kernel C (1024 thr, 8 blocks = one per pot,batch): reduce 64 partials per
// row -> S; finalize f, mix with w, write P; build next step's
// V = exp2((logw + P/eps_next - Mnew)*log2e).
// ---------------------------------------------------------------------------
__global__ __launch_bounds__(1024) void k_combine(float* __restrict__ ws, int stepi)
{
  const int pb = blockIdx.x;
  const int p = pb >> 1, b = pb & 1;
  const int tid = threadIdx.x;

  const float eps = ws[SCHED_OFF + 2 * stepi];
  const float w = ws[SCHED_OFF + 2 * stepi + 1];
  int ni = stepi + 1; if (ni > K_TOTAL - 1) ni = K_TOTAL - 1;
  const float inv_eps_n = 1.0f / ws[SCHED_OFF + 2 * ni];
  const float Mh = ws[MBUF_OFF + pb];

  float* Pp = ws + P_OFF + (p * NB + b) * NPTS;
  float* Vp = ws + V_OFF + (p * NB + b) * NPTS;
  const float* Pt = ws + PART_OFF + pb * PART_PB;

  float h[4];
  float lmax = -1e30f;
#pragma unroll
  for (int k = 0; k < 4; k++) {
    const int r = k * 1024 + tid;
    const float* base = Pt + (r >> 6) * 4096 + (r & 63);
    float s = 0.0f;
#pragma unroll 8
    for (int c = 0; c < 64; c++) s += base[c * 64];
    s = fmaxf(s, 1e-37f);
    float ft = -eps * fmaf(LN2, LOG2F(s), Mh);
    float fo = Pp[r];
    float fn = (w >= 1.0f) ? fo : fmaf(w, fo, (1.0f - w) * ft);
    Pp[r] = fn;
    h[k] = fmaf(fn, inv_eps_n, BASE_LOGW);
    lmax = fmaxf(lmax, h[k]);
  }
  for (int o = 32; o; o >>= 1) lmax = fmaxf(lmax, __shfl_xor(lmax, o, 64));
  __shared__ float red[16];
  if ((tid & 63) == 0) red[tid >> 6] = lmax;
  __syncthreads();
  float M = red[0];
#pragma unroll
  for (int t = 1; t < 16; t++) M = fmaxf(M, red[t]);
#pragma unroll
  for (int k = 0; k < 4; k++) {
    const int r = k * 1024 + tid;
    Vp[r] = EXP2F((h[k] - M) * LOG2E);
  }
  if (tid == 0) ws[MBUF_OFF + pb] = M;
}

// ---------------------------------------------------------------------------
// Kernel D: out = mean_b [ (1/N) sum(f_ba - f_aa) + (1/M) sum(g_ab - g_bb) ]
// ---------------------------------------------------------------------------
__global__ __launch_bounds__(BLOCK) void k_reduce(
    const float* __restrict__ pot, float* __restrict__ out)
{
  const int tid = threadIdx.x;
  double acc = 0.0;
  for (int i = tid; i < POT_SZ; i += BLOCK) {
    double v = (double)pot[i];
    acc += (i < 2 * NB * NPTS) ? v : -v;  // +f_ba +g_ab -f_aa -g_bb
  }
  for (int o = 32; o; o >>= 1) acc += __shfl_xor(acc, o, 64);
  __shared__ double rd[4];
  const int wave = tid >> 6, lane = tid & 63;
  if (lane == 0) rd[wave] = acc;
  __syncthreads();
  if (tid == 0) out[0] = (float)((rd[0] + rd[1] + rd[2] + rd[3]) / (double)(NB * NPTS));
}

extern "C" void kernel_launch(void* const* d_in, const int* in_sizes, int n_in,
                              void* d_out, int out_size, void* d_ws, size_t ws_size,
                              hipStream_t stream)
{
  const float2* x = (const float2*)d_in[0];  // pre (2,4096,2)
  const float2* y = (const float2*)d_in[1];  // gt  (2,4096,2)
  float* ws = (float*)d_ws;

  k_init<<<1, BLOCK, 0, stream>>>(x, y, ws);

  for (int s = 0; s < K_TOTAL; s++) {
    k_tiles<<<GRID_TILES, BLOCK, 0, stream>>>(x, y, ws, s);
    k_combine<<<8, 1024, 0, stream>>>(ws, s);
  }
  k_reduce<<<1, BLOCK, 0, stream>>>(ws + P_OFF, (float*)d_out);
}